// Round 1
// baseline (741.919 us; speedup 1.0000x reference)
//
#include <hip/hip_runtime.h>
#include <hip/hip_bf16.h>

#define HH 200
#define WW 176
#define CIN 256
#define CO 28
#define NBATCH 4
#define NBOX 2048
#define BN_EPS 1e-3f

// ---------------------------------------------------------------------------
// prep: w1t[(ci*9+t)*28+co] = w1[co][ci][t] * bn_scale[co];  shift[co]
// ---------------------------------------------------------------------------
__global__ void prep_k(const float* __restrict__ w1, const float* __restrict__ gamma,
                       const float* __restrict__ beta, const float* __restrict__ mean,
                       const float* __restrict__ var, float* __restrict__ w1t,
                       float* __restrict__ shift)
{
    int tid = blockIdx.x * 256 + threadIdx.x;
    if (tid < CO) {
        float sc = gamma[tid] * rsqrtf(var[tid] + BN_EPS);
        shift[tid] = beta[tid] - mean[tid] * sc;
    }
    if (tid < CIN * 9 * CO) {
        int co = tid % CO;
        int r  = tid / CO;            // r = ci*9 + t
        float sc = gamma[co] * rsqrtf(var[co] + BN_EPS);
        w1t[tid] = w1[co * (CIN * 9) + r] * sc;
    }
}

// ---------------------------------------------------------------------------
// conv3x3 + BN(folded) + ReLU.  One thread = one output pixel, 28 channels.
// y1 layout: (B, H, W, 28) channel-last, so the sampler reads 112B contiguous.
// ---------------------------------------------------------------------------
__global__ __launch_bounds__(256) void conv_bn_relu_k(
    const float* __restrict__ x, const float* __restrict__ w1t,
    const float* __restrict__ shift, float* __restrict__ y1)
{
    const int b  = blockIdx.z;
    const int ox = blockIdx.x * 32 + threadIdx.x;
    const int oy = blockIdx.y * 8  + threadIdx.y;

    int  off[9];
    bool valid[9];
#pragma unroll
    for (int t = 0; t < 9; ++t) {
        int dy = t / 3 - 1, dx = t % 3 - 1;
        int iy = oy + dy,   ix = ox + dx;
        bool v = (iy >= 0) & (iy < HH) & (ix >= 0) & (ix < WW);
        valid[t] = v;
        off[t] = v ? iy * WW + ix : 0;
    }

    float acc[CO];
#pragma unroll
    for (int c = 0; c < CO; ++c) acc[c] = 0.f;

    const float* xb = x + (size_t)b * CIN * HH * WW;

    // prefetched 3x3 neighborhood for current ci
    float v[9];
#pragma unroll
    for (int t = 0; t < 9; ++t) v[t] = valid[t] ? xb[off[t]] : 0.f;

    for (int ci = 0; ci < CIN; ++ci) {
        float vn[9];
        if (ci + 1 < CIN) {
            const float* xc = xb + (size_t)(ci + 1) * (HH * WW);
#pragma unroll
            for (int t = 0; t < 9; ++t) vn[t] = valid[t] ? xc[off[t]] : 0.f;
        }
        const float* wp = w1t + ci * (9 * CO);   // wave-uniform -> s_load weights
#pragma unroll
        for (int t = 0; t < 9; ++t) {
#pragma unroll
            for (int c = 0; c < CO; ++c)
                acc[c] = fmaf(v[t], wp[t * CO + c], acc[c]);
        }
        if (ci + 1 < CIN) {
#pragma unroll
            for (int t = 0; t < 9; ++t) v[t] = vn[t];
        }
    }

    if (ox < WW) {
        float tmp[CO];
#pragma unroll
        for (int c = 0; c < CO; ++c) {
            float z = acc[c] + shift[c];
            tmp[c] = z > 0.f ? z : 0.f;
        }
        float* yp = y1 + (((size_t)(b * HH + oy)) * WW + ox) * CO;
#pragma unroll
        for (int q = 0; q < 7; ++q)
            ((float4*)yp)[q] = make_float4(tmp[4*q], tmp[4*q+1], tmp[4*q+2], tmp[4*q+3]);
    }
}

// ---------------------------------------------------------------------------
// Sampler: thread = (box, k).  Bilinear sample of conv1x1 output = conv1x1 of
// bilinear samples (linear, bias-free).  Mean over k via LDS reduce.
// ---------------------------------------------------------------------------
__global__ __launch_bounds__(224) void sample_k(
    const float* __restrict__ y1, const float* __restrict__ ga,
    const float* __restrict__ w2, float* __restrict__ out)
{
    __shared__ float red[224];
    const int lb  = threadIdx.x / CO;   // local box 0..7
    const int k   = threadIdx.x % CO;   // window index / channel
    const int box = blockIdx.x * 8 + lb;
    const int b   = box >> 11;          // / 2048

    const float* ap = ga + (size_t)box * 7;
    float xg = ap[0], yg = ap[1], wg = ap[3], lg = ap[4], rg = ap[6];
    float c = cosf(rg), s = sinf(rg);

    const int i = k / 7, j = k % 7;
    float xx = ((float)i * (1.f / 3.f) - 0.5f) * wg;
    float yy = ((float)j * (1.f / 6.f) - 0.5f) * lg;
    float xs = (xx * c + yy * s + xg) * 2.5f;
    float ys = (yy * c - xx * s + yg + 40.f) * 2.5f;

    float x0 = floorf(xs), y0 = floorf(ys);
    float wx = xs - x0,    wy = ys - y0;

    // w2 row k (28 floats, 112B -> 16B aligned)
    float w2r[CO];
    const float* w2p = w2 + k * CO;
#pragma unroll
    for (int q = 0; q < 7; ++q) {
        float4 t = ((const float4*)w2p)[q];
        w2r[4*q] = t.x; w2r[4*q+1] = t.y; w2r[4*q+2] = t.z; w2r[4*q+3] = t.w;
    }

    float val = 0.f;
    const float* yb = y1 + (size_t)b * HH * WW * CO;
#pragma unroll
    for (int cor = 0; cor < 4; ++cor) {
        float yf = y0 + (float)(cor >> 1);
        float xf = x0 + (float)(cor & 1);
        float cw = ((cor & 1) ? wx : 1.f - wx) * ((cor >> 1) ? wy : 1.f - wy);
        if (yf >= 0.f && yf <= (float)(HH - 1) && xf >= 0.f && xf <= (float)(WW - 1)) {
            int yi = (int)yf, xi = (int)xf;
            const float* p = yb + ((size_t)yi * WW + xi) * CO;
            float d = 0.f;
#pragma unroll
            for (int q = 0; q < 7; ++q) {
                float4 t = ((const float4*)p)[q];
                d = fmaf(w2r[4*q],   t.x, d);
                d = fmaf(w2r[4*q+1], t.y, d);
                d = fmaf(w2r[4*q+2], t.z, d);
                d = fmaf(w2r[4*q+3], t.w, d);
            }
            val = fmaf(cw, d, val);
        }
    }

    red[threadIdx.x] = val;
    __syncthreads();
    if (k == 0) {
        float sum = 0.f;
#pragma unroll
        for (int q = 0; q < CO; ++q) sum += red[lb * CO + q];
        out[box] = sum * (1.f / 28.f);
    }
}

// ---------------------------------------------------------------------------
extern "C" void kernel_launch(void* const* d_in, const int* in_sizes, int n_in,
                              void* d_out, int out_size, void* d_ws, size_t ws_size,
                              hipStream_t stream) {
    const float* x     = (const float*)d_in[0];
    const float* ga    = (const float*)d_in[1];
    const float* w1    = (const float*)d_in[2];
    const float* gamma = (const float*)d_in[3];
    const float* beta  = (const float*)d_in[4];
    const float* mean  = (const float*)d_in[5];
    const float* var   = (const float*)d_in[6];
    const float* w2    = (const float*)d_in[7];
    float* out = (float*)d_out;

    float* ws    = (float*)d_ws;
    float* w1t   = ws;                 // 64512 floats
    float* shift = ws + 64512;         // 28 floats
    float* y1    = ws + 65536;         // 4*200*176*28 floats (channel-last)

    prep_k<<<(CIN * 9 * CO + 255) / 256, 256, 0, stream>>>(w1, gamma, beta, mean, var, w1t, shift);

    dim3 cb(32, 8);
    dim3 cg((WW + 31) / 32, HH / 8, NBATCH);
    conv_bn_relu_k<<<cg, cb, 0, stream>>>(x, w1t, shift, y1);

    sample_k<<<(NBATCH * NBOX) / 8, 224, 0, stream>>>(y1, ga, w2, out);
}

// Round 2
// 124.485 us; speedup vs baseline: 5.9599x; 5.9599x over previous
//
#include <hip/hip_runtime.h>
#include <hip/hip_bf16.h>

#define HH 200
#define WW 176
#define CIN 256
#define CO 28
#define BN_EPS 1e-3f

typedef __attribute__((ext_vector_type(8))) short short8;
typedef __attribute__((ext_vector_type(4))) float f32x4;

static __device__ __forceinline__ ushort f2bf(float f) {
    __hip_bfloat16 h = __float2bfloat16(f);
    return __builtin_bit_cast(ushort, h);
}

// ---------------------------------------------------------------------------
// prep: w1b in per-lane B-fragment order [t][h][n][lane][j] (bf16, BN-folded),
// plus shift[28].
//   co = n*16 + (lane&15), ci = h*32 + (lane>>4)*8 + j
// ---------------------------------------------------------------------------
__global__ void prep_k(const float* __restrict__ w1, const float* __restrict__ gamma,
                       const float* __restrict__ beta, const float* __restrict__ mean,
                       const float* __restrict__ var, ushort* __restrict__ w1b,
                       float* __restrict__ shift)
{
    int idx = blockIdx.x * 256 + threadIdx.x;
    if (idx < CO) {
        float sc = gamma[idx] * rsqrtf(var[idx] + BN_EPS);
        shift[idx] = beta[idx] - mean[idx] * sc;
    }
    if (idx < 9 * 8 * 2 * 64 * 8) {
        int j  = idx & 7;
        int l  = (idx >> 3) & 63;
        int n  = (idx >> 9) & 1;
        int h  = (idx >> 10) & 7;
        int t  = idx >> 13;
        int co = n * 16 + (l & 15);
        int ci = h * 32 + (l >> 4) * 8 + j;
        float v = 0.f;
        if (co < CO) {
            float sc = gamma[co] * rsqrtf(var[co] + BN_EPS);
            v = w1[(co * CIN + ci) * 9 + t] * sc;
        }
        w1b[idx] = f2bf(v);
    }
}

// ---------------------------------------------------------------------------
// Implicit-GEMM conv3x3 + BN + ReLU via bf16 MFMA.
// Block: 16x16 output tile, 4 waves. Wave w owns tile rows 4w..4w+3 and
// stages ci-octet w.  LDS halo tile: 18x18 pixels x 32ci bf16, 16B-swizzled.
// ---------------------------------------------------------------------------
__global__ __launch_bounds__(256, 3) void conv_mfma_k(
    const float* __restrict__ x, const ushort* __restrict__ w1b,
    const float* __restrict__ shift, float* __restrict__ y1)
{
    __shared__ uint4 sbuf[2][324 * 4];   // 2 x 20736 B

    const int tid  = threadIdx.x;
    const int lane = tid & 63;
    const int w    = tid >> 6;           // wave id == ci octet
    const int x0   = blockIdx.x * 16;
    const int y0   = blockIdx.y * 16;
    const int b    = blockIdx.z;

    const float* xb = x + (size_t)b * CIN * HH * WW;

    f32x4 acc[4][2];
#pragma unroll
    for (int m = 0; m < 4; ++m)
#pragma unroll
        for (int n = 0; n < 2; ++n)
            acc[m][n] = (f32x4){0.f, 0.f, 0.f, 0.f};

    for (int h = 0; h < 8; ++h) {
        // ---- stage chunk h (32 ci) into sbuf[h&1], transposed to pixel-major
        const float* plane0 = xb + (size_t)(h * 32 + w * 8) * (HH * WW);
#pragma unroll
        for (int it = 0; it < 6; ++it) {
            int p = it * 64 + lane;
            if (p < 324) {
                int r  = p / 18;
                int c  = p - r * 18;
                int gy = y0 + r - 1;
                int gx = x0 + c - 1;
                bool valid = (gy >= 0) & (gy < HH) & (gx >= 0) & (gx < WW);
                int off = valid ? (gy * WW + gx) : 0;
                ushort u[8];
#pragma unroll
                for (int j = 0; j < 8; ++j) {
                    float v = plane0[(size_t)j * (HH * WW) + off];
                    u[j] = f2bf(valid ? v : 0.f);
                }
                uint4 val;
                val.x = (uint)u[0] | ((uint)u[1] << 16);
                val.y = (uint)u[2] | ((uint)u[3] << 16);
                val.z = (uint)u[4] | ((uint)u[5] << 16);
                val.w = (uint)u[6] | ((uint)u[7] << 16);
                sbuf[h & 1][p * 4 + ((w + p) & 3)] = val;
            }
        }
        __syncthreads();

        // ---- 9 taps x (4 M-frags x 2 N-frags) MFMA
        const uint4* sb = sbuf[h & 1];
#pragma unroll
        for (int t = 0; t < 9; ++t) {
            const int dy = t / 3 - 1, dx = t % 3 - 1;
            short8 bfr[2];
#pragma unroll
            for (int n = 0; n < 2; ++n)
                bfr[n] = *(const short8*)(w1b + (size_t)(((t * 8 + h) * 2 + n) * 64 + lane) * 8);
#pragma unroll
            for (int m = 0; m < 4; ++m) {
                int p = (4 * w + m + dy + 1) * 18 + (lane & 15) + dx + 1;
                uint4 av = sb[p * 4 + (((lane >> 4) + p) & 3)];
                short8 af = __builtin_bit_cast(short8, av);
                acc[m][0] = __builtin_amdgcn_mfma_f32_16x16x32_bf16(af, bfr[0], acc[m][0], 0, 0, 0);
                acc[m][1] = __builtin_amdgcn_mfma_f32_16x16x32_bf16(af, bfr[1], acc[m][1], 0, 0, 0);
            }
        }
        __syncthreads();
    }

    // ---- epilogue: + shift, ReLU, store channel-last y1
    const int co0 = lane & 15;
    const int co1 = 16 + co0;
    const float s0 = shift[co0];
    const float s1 = (co1 < CO) ? shift[co1] : 0.f;
#pragma unroll
    for (int m = 0; m < 4; ++m) {
        int gy = y0 + 4 * w + m;
        if (gy < HH) {
#pragma unroll
            for (int reg = 0; reg < 4; ++reg) {
                int gx = x0 + (lane >> 4) * 4 + reg;
                float* yp = y1 + ((size_t)(b * HH + gy) * WW + gx) * CO;
                float v0 = acc[m][0][reg] + s0;
                yp[co0] = v0 > 0.f ? v0 : 0.f;
                if (co1 < CO) {
                    float v1 = acc[m][1][reg] + s1;
                    yp[co1] = v1 > 0.f ? v1 : 0.f;
                }
            }
        }
    }
}

// ---------------------------------------------------------------------------
// Sampler: thread = (box, k).  Bilinear sample of conv1x1 output = conv1x1 of
// bilinear samples (linear, bias-free).  Mean over k via LDS reduce.
// ---------------------------------------------------------------------------
__global__ __launch_bounds__(224) void sample_k(
    const float* __restrict__ y1, const float* __restrict__ ga,
    const float* __restrict__ w2, float* __restrict__ out)
{
    __shared__ float red[224];
    const int lb  = threadIdx.x / CO;   // local box 0..7
    const int k   = threadIdx.x % CO;   // window index / channel
    const int box = blockIdx.x * 8 + lb;
    const int b   = box >> 11;          // / 2048

    const float* ap = ga + (size_t)box * 7;
    float xg = ap[0], yg = ap[1], wg = ap[3], lg = ap[4], rg = ap[6];
    float c = cosf(rg), s = sinf(rg);

    const int i = k / 7, j = k % 7;
    float xx = ((float)i * (1.f / 3.f) - 0.5f) * wg;
    float yy = ((float)j * (1.f / 6.f) - 0.5f) * lg;
    float xs = (xx * c + yy * s + xg) * 2.5f;
    float ys = (yy * c - xx * s + yg + 40.f) * 2.5f;

    float x0 = floorf(xs), y0 = floorf(ys);
    float wx = xs - x0,    wy = ys - y0;

    float w2r[CO];
    const float* w2p = w2 + k * CO;
#pragma unroll
    for (int q = 0; q < 7; ++q) {
        float4 t = ((const float4*)w2p)[q];
        w2r[4*q] = t.x; w2r[4*q+1] = t.y; w2r[4*q+2] = t.z; w2r[4*q+3] = t.w;
    }

    float val = 0.f;
    const float* yb = y1 + (size_t)b * HH * WW * CO;
#pragma unroll
    for (int cor = 0; cor < 4; ++cor) {
        float yf = y0 + (float)(cor >> 1);
        float xf = x0 + (float)(cor & 1);
        float cw = ((cor & 1) ? wx : 1.f - wx) * ((cor >> 1) ? wy : 1.f - wy);
        if (yf >= 0.f && yf <= (float)(HH - 1) && xf >= 0.f && xf <= (float)(WW - 1)) {
            int yi = (int)yf, xi = (int)xf;
            const float* p = yb + ((size_t)yi * WW + xi) * CO;
            float d = 0.f;
#pragma unroll
            for (int q = 0; q < 7; ++q) {
                float4 t = ((const float4*)p)[q];
                d = fmaf(w2r[4*q],   t.x, d);
                d = fmaf(w2r[4*q+1], t.y, d);
                d = fmaf(w2r[4*q+2], t.z, d);
                d = fmaf(w2r[4*q+3], t.w, d);
            }
            val = fmaf(cw, d, val);
        }
    }

    red[threadIdx.x] = val;
    __syncthreads();
    if (k == 0) {
        float sum = 0.f;
#pragma unroll
        for (int q = 0; q < CO; ++q) sum += red[lb * CO + q];
        out[box] = sum * (1.f / 28.f);
    }
}

// ---------------------------------------------------------------------------
extern "C" void kernel_launch(void* const* d_in, const int* in_sizes, int n_in,
                              void* d_out, int out_size, void* d_ws, size_t ws_size,
                              hipStream_t stream) {
    const float* x     = (const float*)d_in[0];
    const float* ga    = (const float*)d_in[1];
    const float* w1    = (const float*)d_in[2];
    const float* gamma = (const float*)d_in[3];
    const float* beta  = (const float*)d_in[4];
    const float* mean  = (const float*)d_in[5];
    const float* var   = (const float*)d_in[6];
    const float* w2    = (const float*)d_in[7];
    float* out = (float*)d_out;

    ushort* w1b  = (ushort*)d_ws;                          // 147456 B
    float*  shift = (float*)((char*)d_ws + 147456);        // 112 B
    float*  y1    = (float*)((char*)d_ws + 147968);        // 4*200*176*28 f32

    prep_k<<<(9 * 8 * 2 * 64 * 8 + 255) / 256, 256, 0, stream>>>(
        w1, gamma, beta, mean, var, w1b, shift);

    dim3 cg(WW / 16, (HH + 15) / 16, 4);
    conv_mfma_k<<<cg, 256, 0, stream>>>(x, w1b, shift, y1);

    sample_k<<<(4 * 2048) / 8, 224, 0, stream>>>(y1, ga, w2, out);
}

// Round 3
// 91.618 us; speedup vs baseline: 8.0980x; 1.3587x over previous
//
#include <hip/hip_runtime.h>
#include <hip/hip_bf16.h>

#define HH 200
#define WW 176
#define CIN 256
#define CO 28
#define BN_EPS 1e-3f

typedef __attribute__((ext_vector_type(8))) short short8;
typedef __attribute__((ext_vector_type(4))) float f32x4;

static __device__ __forceinline__ ushort f2bf(float f) {
    __hip_bfloat16 h = __float2bfloat16(f);
    return __builtin_bit_cast(ushort, h);
}

// ---------------------------------------------------------------------------
// prep: w1b in per-lane B-fragment order [t][h][n][lane][j] (bf16, BN-folded),
// plus shift[28].
//   co = n*16 + (lane&15), ci = h*32 + (lane>>4)*8 + j
// ---------------------------------------------------------------------------
__global__ void prep_k(const float* __restrict__ w1, const float* __restrict__ gamma,
                       const float* __restrict__ beta, const float* __restrict__ mean,
                       const float* __restrict__ var, ushort* __restrict__ w1b,
                       float* __restrict__ shift)
{
    int idx = blockIdx.x * 256 + threadIdx.x;
    if (idx < CO) {
        float sc = gamma[idx] * rsqrtf(var[idx] + BN_EPS);
        shift[idx] = beta[idx] - mean[idx] * sc;
    }
    if (idx < 9 * 8 * 2 * 64 * 8) {
        int j  = idx & 7;
        int l  = (idx >> 3) & 63;
        int n  = (idx >> 9) & 1;
        int h  = (idx >> 10) & 7;
        int t  = idx >> 13;
        int co = n * 16 + (l & 15);
        int ci = h * 32 + (l >> 4) * 8 + j;
        float v = 0.f;
        if (co < CO) {
            float sc = gamma[co] * rsqrtf(var[co] + BN_EPS);
            v = w1[(co * CIN + ci) * 9 + t] * sc;
        }
        w1b[idx] = f2bf(v);
    }
}

// ---------------------------------------------------------------------------
// Implicit-GEMM conv3x3 + BN + ReLU via bf16 MFMA, software-pipelined:
//   issue global loads(h+1) -> MFMA(h) -> convert+ds_write(h+1) -> barrier
// Block: 16x16 output tile, 4 waves; wave w stages ci-octet w.
// LDS halo tile 18x18 px x 32ci bf16, 16B-unit swizzle (conflict-free).
// ---------------------------------------------------------------------------
__global__ __launch_bounds__(256, 3) void conv_mfma_k(
    const float* __restrict__ x, const ushort* __restrict__ w1b,
    const float* __restrict__ shift, float* __restrict__ y1)
{
    __shared__ uint4 sbuf[2][324 * 4];   // 2 x 20736 B

    const int tid  = threadIdx.x;
    const int lane = tid & 63;
    const int w    = tid >> 6;           // wave id == ci octet

    // XCD-aware bijective block swizzle (572 blocks, 8 XCDs): x-adjacent
    // tiles land on the same XCD -> halo cache lines shared in one L2.
    const int NB = 11 * 13 * 4;
    const int q = NB / 8, r = NB % 8;    // 71, 4
    const int bid  = blockIdx.x;
    const int xcd  = bid & 7;
    const int rank = bid >> 3;
    const int tile = (xcd < r ? xcd * (q + 1) : r * (q + 1) + (xcd - r) * q) + rank;

    const int tx = tile % 11;
    const int rem = tile / 11;
    const int ty = rem % 13;
    const int b  = rem / 13;
    const int x0 = tx * 16, y0 = ty * 16;

    const float* xb = x + (size_t)b * CIN * HH * WW;

    // chunk-invariant per-lane staging geometry
    int  soff[6]; bool sval[6]; bool sp[6];
#pragma unroll
    for (int it = 0; it < 6; ++it) {
        int p = it * 64 + lane;
        sp[it] = p < 324;
        int rr = p / 18, cc = p - rr * 18;
        int gy = y0 + rr - 1, gx = x0 + cc - 1;
        bool v = (gy >= 0) & (gy < HH) & (gx >= 0) & (gx < WW) & sp[it];
        sval[it] = v;
        soff[it] = v ? gy * WW + gx : 0;
    }

    float pre[6][8];

    auto issue = [&](int h) {
        const float* pl = xb + (size_t)(h * 32 + w * 8) * (HH * WW);
#pragma unroll
        for (int it = 0; it < 6; ++it) {
            if (sp[it]) {
#pragma unroll
                for (int j = 0; j < 8; ++j)
                    pre[it][j] = pl[(size_t)j * (HH * WW) + soff[it]];
            }
        }
    };

    auto wr = [&](int h) {
#pragma unroll
        for (int it = 0; it < 6; ++it) {
            if (sp[it]) {
                int p = it * 64 + lane;
                ushort u[8];
#pragma unroll
                for (int j = 0; j < 8; ++j)
                    u[j] = sval[it] ? f2bf(pre[it][j]) : (ushort)0;
                uint4 val;
                val.x = (uint)u[0] | ((uint)u[1] << 16);
                val.y = (uint)u[2] | ((uint)u[3] << 16);
                val.z = (uint)u[4] | ((uint)u[5] << 16);
                val.w = (uint)u[6] | ((uint)u[7] << 16);
                sbuf[h & 1][p * 4 + ((w + p) & 3)] = val;
            }
        }
    };

    f32x4 acc[4][2];
#pragma unroll
    for (int m = 0; m < 4; ++m)
#pragma unroll
        for (int n = 0; n < 2; ++n)
            acc[m][n] = (f32x4){0.f, 0.f, 0.f, 0.f};

    auto compute = [&](int h) {
        const uint4* sb = sbuf[h & 1];
#pragma unroll
        for (int t = 0; t < 9; ++t) {
            const int dy = t / 3 - 1, dx = t % 3 - 1;
            short8 bfr[2];
#pragma unroll
            for (int n = 0; n < 2; ++n)
                bfr[n] = *(const short8*)(w1b + (size_t)(((t * 8 + h) * 2 + n) * 64 + lane) * 8);
#pragma unroll
            for (int m = 0; m < 4; ++m) {
                int p = (4 * w + m + dy + 1) * 18 + (lane & 15) + dx + 1;
                uint4 av = sb[p * 4 + (((lane >> 4) + p) & 3)];
                short8 af = __builtin_bit_cast(short8, av);
                acc[m][0] = __builtin_amdgcn_mfma_f32_16x16x32_bf16(af, bfr[0], acc[m][0], 0, 0, 0);
                acc[m][1] = __builtin_amdgcn_mfma_f32_16x16x32_bf16(af, bfr[1], acc[m][1], 0, 0, 0);
            }
        }
    };

    // prologue
    issue(0);
    wr(0);
    __syncthreads();

    // pipelined main loop: one barrier per chunk
#pragma unroll 1
    for (int h = 0; h < 7; ++h) {
        issue(h + 1);        // global loads for next chunk (in flight)
        compute(h);          // MFMA on current chunk (hides the latency)
        wr(h + 1);           // waitcnt + convert + ds_write into buf^1
        __syncthreads();
    }
    compute(7);

    // epilogue: + shift, ReLU, store channel-last y1
    const int co0 = lane & 15;
    const int co1 = 16 + co0;
    const float s0 = shift[co0];
    const float s1 = (co1 < CO) ? shift[co1] : 0.f;
#pragma unroll
    for (int m = 0; m < 4; ++m) {
        int gy = y0 + 4 * w + m;
        if (gy < HH) {
#pragma unroll
            for (int reg = 0; reg < 4; ++reg) {
                int gx = x0 + (lane >> 4) * 4 + reg;
                float* yp = y1 + ((size_t)(b * HH + gy) * WW + gx) * CO;
                float v0 = acc[m][0][reg] + s0;
                yp[co0] = v0 > 0.f ? v0 : 0.f;
                if (co1 < CO) {
                    float v1 = acc[m][1][reg] + s1;
                    yp[co1] = v1 > 0.f ? v1 : 0.f;
                }
            }
        }
    }
}

// ---------------------------------------------------------------------------
// Sampler: thread = (box, k).  Bilinear sample of conv1x1 output = conv1x1 of
// bilinear samples (linear, bias-free).  Mean over k via LDS reduce.
// ---------------------------------------------------------------------------
__global__ __launch_bounds__(224) void sample_k(
    const float* __restrict__ y1, const float* __restrict__ ga,
    const float* __restrict__ w2, float* __restrict__ out)
{
    __shared__ float red[224];
    const int lb  = threadIdx.x / CO;   // local box 0..7
    const int k   = threadIdx.x % CO;   // window index / channel
    const int box = blockIdx.x * 8 + lb;
    const int b   = box >> 11;          // / 2048

    const float* ap = ga + (size_t)box * 7;
    float xg = ap[0], yg = ap[1], wg = ap[3], lg = ap[4], rg = ap[6];
    float c = cosf(rg), s = sinf(rg);

    const int i = k / 7, j = k % 7;
    float xx = ((float)i * (1.f / 3.f) - 0.5f) * wg;
    float yy = ((float)j * (1.f / 6.f) - 0.5f) * lg;
    float xs = (xx * c + yy * s + xg) * 2.5f;
    float ys = (yy * c - xx * s + yg + 40.f) * 2.5f;

    float x0 = floorf(xs), y0 = floorf(ys);
    float wx = xs - x0,    wy = ys - y0;

    float w2r[CO];
    const float* w2p = w2 + k * CO;
#pragma unroll
    for (int q = 0; q < 7; ++q) {
        float4 t = ((const float4*)w2p)[q];
        w2r[4*q] = t.x; w2r[4*q+1] = t.y; w2r[4*q+2] = t.z; w2r[4*q+3] = t.w;
    }

    float val = 0.f;
    const float* yb = y1 + (size_t)b * HH * WW * CO;
#pragma unroll
    for (int cor = 0; cor < 4; ++cor) {
        float yf = y0 + (float)(cor >> 1);
        float xf = x0 + (float)(cor & 1);
        float cw = ((cor & 1) ? wx : 1.f - wx) * ((cor >> 1) ? wy : 1.f - wy);
        if (yf >= 0.f && yf <= (float)(HH - 1) && xf >= 0.f && xf <= (float)(WW - 1)) {
            int yi = (int)yf, xi = (int)xf;
            const float* p = yb + ((size_t)yi * WW + xi) * CO;
            float d = 0.f;
#pragma unroll
            for (int q = 0; q < 7; ++q) {
                float4 t = ((const float4*)p)[q];
                d = fmaf(w2r[4*q],   t.x, d);
                d = fmaf(w2r[4*q+1], t.y, d);
                d = fmaf(w2r[4*q+2], t.z, d);
                d = fmaf(w2r[4*q+3], t.w, d);
            }
            val = fmaf(cw, d, val);
        }
    }

    red[threadIdx.x] = val;
    __syncthreads();
    if (k == 0) {
        float sum = 0.f;
#pragma unroll
        for (int q = 0; q < CO; ++q) sum += red[lb * CO + q];
        out[box] = sum * (1.f / 28.f);
    }
}

// ---------------------------------------------------------------------------
extern "C" void kernel_launch(void* const* d_in, const int* in_sizes, int n_in,
                              void* d_out, int out_size, void* d_ws, size_t ws_size,
                              hipStream_t stream) {
    const float* x     = (const float*)d_in[0];
    const float* ga    = (const float*)d_in[1];
    const float* w1    = (const float*)d_in[2];
    const float* gamma = (const float*)d_in[3];
    const float* beta  = (const float*)d_in[4];
    const float* mean  = (const float*)d_in[5];
    const float* var   = (const float*)d_in[6];
    const float* w2    = (const float*)d_in[7];
    float* out = (float*)d_out;

    ushort* w1b   = (ushort*)d_ws;                         // 147456 B
    float*  shift = (float*)((char*)d_ws + 147456);        // 112 B
    float*  y1    = (float*)((char*)d_ws + 147968);        // 4*200*176*28 f32

    prep_k<<<(9 * 8 * 2 * 64 * 8 + 255) / 256, 256, 0, stream>>>(
        w1, gamma, beta, mean, var, w1b, shift);

    conv_mfma_k<<<11 * 13 * 4, 256, 0, stream>>>(x, w1b, shift, y1);

    sample_k<<<(4 * 2048) / 8, 224, 0, stream>>>(y1, ga, w2, out);
}

// Round 4
// 89.083 us; speedup vs baseline: 8.3284x; 1.0285x over previous
//
#include <hip/hip_runtime.h>
#include <hip/hip_bf16.h>

#define HH 200
#define WW 176
#define CIN 256
#define CO 28
#define BN_EPS 1e-3f

typedef __attribute__((ext_vector_type(8))) short short8;
typedef __attribute__((ext_vector_type(4))) float f32x4;

static __device__ __forceinline__ ushort f2bf(float f) {
    __hip_bfloat16 h = __float2bfloat16(f);
    return __builtin_bit_cast(ushort, h);
}

// ---------------------------------------------------------------------------
// prep: w1b in per-lane B-fragment order [t][h][n][lane][j] (bf16, BN-folded),
// plus shift[28].
//   co = n*16 + (lane&15), ci = h*32 + (lane>>4)*8 + j
// ---------------------------------------------------------------------------
__global__ void prep_k(const float* __restrict__ w1, const float* __restrict__ gamma,
                       const float* __restrict__ beta, const float* __restrict__ mean,
                       const float* __restrict__ var, ushort* __restrict__ w1b,
                       float* __restrict__ shift)
{
    int idx = blockIdx.x * 256 + threadIdx.x;
    if (idx < CO) {
        float sc = gamma[idx] * rsqrtf(var[idx] + BN_EPS);
        shift[idx] = beta[idx] - mean[idx] * sc;
    }
    if (idx < 9 * 8 * 2 * 64 * 8) {
        int j  = idx & 7;
        int l  = (idx >> 3) & 63;
        int n  = (idx >> 9) & 1;
        int h  = (idx >> 10) & 7;
        int t  = idx >> 13;
        int co = n * 16 + (l & 15);
        int ci = h * 32 + (l >> 4) * 8 + j;
        float v = 0.f;
        if (co < CO) {
            float sc = gamma[co] * rsqrtf(var[co] + BN_EPS);
            v = w1[(co * CIN + ci) * 9 + t] * sc;
        }
        w1b[idx] = f2bf(v);
    }
}

// ---------------------------------------------------------------------------
// Implicit-GEMM conv3x3 + BN + ReLU via bf16 MFMA, software-pipelined.
// Tile 16x8 px (one M-frag per image row), 4 waves; wave w owns tile rows
// {2w, 2w+1} and stages ci-octet w. Halo 18x10 px x 32ci bf16 in LDS,
// 16B-unit swizzle. Grid 11x25x4 = 1100 blocks, 4 blocks/CU resident.
// ---------------------------------------------------------------------------
__global__ __launch_bounds__(256, 4) void conv_mfma_k(
    const float* __restrict__ x, const ushort* __restrict__ w1b,
    const float* __restrict__ shift, float* __restrict__ y1)
{
    __shared__ uint4 sbuf[2][180 * 4];   // 2 x 11520 B

    const int tid  = threadIdx.x;
    const int lane = tid & 63;
    const int w    = tid >> 6;           // wave id == ci octet

    // XCD-aware bijective block swizzle (1100 blocks, 8 XCDs)
    const int NB = 11 * 25 * 4;
    const int q = NB / 8, r = NB % 8;    // 137, 4
    const int bid  = blockIdx.x;
    const int xcd  = bid & 7;
    const int rank = bid >> 3;
    const int tile = (xcd < r ? xcd * (q + 1) : r * (q + 1) + (xcd - r) * q) + rank;

    const int tx  = tile % 11;
    const int rem = tile / 11;
    const int ty  = rem % 25;
    const int b   = rem / 25;
    const int x0  = tx * 16, y0 = ty * 8;

    const float* xb = x + (size_t)b * CIN * HH * WW;

    // chunk-invariant per-lane staging geometry (halo 18 wide x 10 tall)
    int  soff[3]; bool sval[3]; bool sp[3];
#pragma unroll
    for (int it = 0; it < 3; ++it) {
        int p = it * 64 + lane;
        sp[it] = p < 180;
        int rr = p / 18, cc = p - rr * 18;
        int gy = y0 + rr - 1, gx = x0 + cc - 1;
        bool v = (gy >= 0) & (gy < HH) & (gx >= 0) & (gx < WW) & sp[it];
        sval[it] = v;
        soff[it] = v ? gy * WW + gx : 0;
    }

    float pre[3][8];

    auto issue = [&](int h) {
        const float* pl = xb + (size_t)(h * 32 + w * 8) * (HH * WW);
#pragma unroll
        for (int it = 0; it < 3; ++it) {
            if (sp[it]) {
#pragma unroll
                for (int j = 0; j < 8; ++j)
                    pre[it][j] = pl[(size_t)j * (HH * WW) + soff[it]];
            }
        }
    };

    auto wr = [&](int h) {
#pragma unroll
        for (int it = 0; it < 3; ++it) {
            if (sp[it]) {
                int p = it * 64 + lane;
                ushort u[8];
#pragma unroll
                for (int j = 0; j < 8; ++j)
                    u[j] = sval[it] ? f2bf(pre[it][j]) : (ushort)0;
                uint4 val;
                val.x = (uint)u[0] | ((uint)u[1] << 16);
                val.y = (uint)u[2] | ((uint)u[3] << 16);
                val.z = (uint)u[4] | ((uint)u[5] << 16);
                val.w = (uint)u[6] | ((uint)u[7] << 16);
                sbuf[h & 1][p * 4 + ((w + p) & 3)] = val;
            }
        }
    };

    f32x4 acc[2][2];
#pragma unroll
    for (int m = 0; m < 2; ++m)
#pragma unroll
        for (int n = 0; n < 2; ++n)
            acc[m][n] = (f32x4){0.f, 0.f, 0.f, 0.f};

    auto compute = [&](int h) {
        const uint4* sb = sbuf[h & 1];
#pragma unroll
        for (int t = 0; t < 9; ++t) {
            const int dy = t / 3 - 1, dx = t % 3 - 1;
            short8 bfr[2];
#pragma unroll
            for (int n = 0; n < 2; ++n)
                bfr[n] = *(const short8*)(w1b + (size_t)(((t * 8 + h) * 2 + n) * 64 + lane) * 8);
#pragma unroll
            for (int m = 0; m < 2; ++m) {
                int p = (2 * w + m + dy + 1) * 18 + (lane & 15) + dx + 1;
                uint4 av = sb[p * 4 + (((lane >> 4) + p) & 3)];
                short8 af = __builtin_bit_cast(short8, av);
                acc[m][0] = __builtin_amdgcn_mfma_f32_16x16x32_bf16(af, bfr[0], acc[m][0], 0, 0, 0);
                acc[m][1] = __builtin_amdgcn_mfma_f32_16x16x32_bf16(af, bfr[1], acc[m][1], 0, 0, 0);
            }
        }
    };

    // prologue
    issue(0);
    wr(0);
    __syncthreads();

    // pipelined main loop: one barrier per chunk
#pragma unroll 1
    for (int h = 0; h < 7; ++h) {
        issue(h + 1);        // global loads for next chunk (in flight)
        compute(h);          // MFMA on current chunk (hides the latency)
        wr(h + 1);           // waitcnt + convert + ds_write into buf^1
        __syncthreads();
    }
    compute(7);

    // epilogue: + shift, ReLU, store channel-last y1
    const int co0 = lane & 15;
    const int co1 = 16 + co0;
    const float s0 = shift[co0];
    const float s1 = (co1 < CO) ? shift[co1] : 0.f;
#pragma unroll
    for (int m = 0; m < 2; ++m) {
        int gy = y0 + 2 * w + m;
#pragma unroll
        for (int reg = 0; reg < 4; ++reg) {
            int gx = x0 + (lane >> 4) * 4 + reg;
            float* yp = y1 + ((size_t)(b * HH + gy) * WW + gx) * CO;
            float v0 = acc[m][0][reg] + s0;
            yp[co0] = v0 > 0.f ? v0 : 0.f;
            if (co1 < CO) {
                float v1 = acc[m][1][reg] + s1;
                yp[co1] = v1 > 0.f ? v1 : 0.f;
            }
        }
    }
}

// ---------------------------------------------------------------------------
// Sampler: thread = (box, k).  Bilinear sample of conv1x1 output = conv1x1 of
// bilinear samples (linear, bias-free).  Mean over k via LDS reduce.
// ---------------------------------------------------------------------------
__global__ __launch_bounds__(224) void sample_k(
    const float* __restrict__ y1, const float* __restrict__ ga,
    const float* __restrict__ w2, float* __restrict__ out)
{
    __shared__ float red[224];
    const int lb  = threadIdx.x / CO;   // local box 0..7
    const int k   = threadIdx.x % CO;   // window index / channel
    const int box = blockIdx.x * 8 + lb;
    const int b   = box >> 11;          // / 2048

    const float* ap = ga + (size_t)box * 7;
    float xg = ap[0], yg = ap[1], wg = ap[3], lg = ap[4], rg = ap[6];
    float c = cosf(rg), s = sinf(rg);

    const int i = k / 7, j = k % 7;
    float xx = ((float)i * (1.f / 3.f) - 0.5f) * wg;
    float yy = ((float)j * (1.f / 6.f) - 0.5f) * lg;
    float xs = (xx * c + yy * s + xg) * 2.5f;
    float ys = (yy * c - xx * s + yg + 40.f) * 2.5f;

    float x0 = floorf(xs), y0 = floorf(ys);
    float wx = xs - x0,    wy = ys - y0;

    float w2r[CO];
    const float* w2p = w2 + k * CO;
#pragma unroll
    for (int q = 0; q < 7; ++q) {
        float4 t = ((const float4*)w2p)[q];
        w2r[4*q] = t.x; w2r[4*q+1] = t.y; w2r[4*q+2] = t.z; w2r[4*q+3] = t.w;
    }

    float val = 0.f;
    const float* yb = y1 + (size_t)b * HH * WW * CO;
#pragma unroll
    for (int cor = 0; cor < 4; ++cor) {
        float yf = y0 + (float)(cor >> 1);
        float xf = x0 + (float)(cor & 1);
        float cw = ((cor & 1) ? wx : 1.f - wx) * ((cor >> 1) ? wy : 1.f - wy);
        if (yf >= 0.f && yf <= (float)(HH - 1) && xf >= 0.f && xf <= (float)(WW - 1)) {
            int yi = (int)yf, xi = (int)xf;
            const float* p = yb + ((size_t)yi * WW + xi) * CO;
            float d = 0.f;
#pragma unroll
            for (int q = 0; q < 7; ++q) {
                float4 t = ((const float4*)p)[q];
                d = fmaf(w2r[4*q],   t.x, d);
                d = fmaf(w2r[4*q+1], t.y, d);
                d = fmaf(w2r[4*q+2], t.z, d);
                d = fmaf(w2r[4*q+3], t.w, d);
            }
            val = fmaf(cw, d, val);
        }
    }

    red[threadIdx.x] = val;
    __syncthreads();
    if (k == 0) {
        float sum = 0.f;
#pragma unroll
        for (int q = 0; q < CO; ++q) sum += red[lb * CO + q];
        out[box] = sum * (1.f / 28.f);
    }
}

// ---------------------------------------------------------------------------
extern "C" void kernel_launch(void* const* d_in, const int* in_sizes, int n_in,
                              void* d_out, int out_size, void* d_ws, size_t ws_size,
                              hipStream_t stream) {
    const float* x     = (const float*)d_in[0];
    const float* ga    = (const float*)d_in[1];
    const float* w1    = (const float*)d_in[2];
    const float* gamma = (const float*)d_in[3];
    const float* beta  = (const float*)d_in[4];
    const float* mean  = (const float*)d_in[5];
    const float* var   = (const float*)d_in[6];
    const float* w2    = (const float*)d_in[7];
    float* out = (float*)d_out;

    ushort* w1b   = (ushort*)d_ws;                         // 147456 B
    float*  shift = (float*)((char*)d_ws + 147456);        // 112 B
    float*  y1    = (float*)((char*)d_ws + 147968);        // 4*200*176*28 f32

    prep_k<<<(9 * 8 * 2 * 64 * 8 + 255) / 256, 256, 0, stream>>>(
        w1, gamma, beta, mean, var, w1b, shift);

    conv_mfma_k<<<11 * 25 * 4, 256, 0, stream>>>(x, w1b, shift, y1);

    sample_k<<<(4 * 2048) / 8, 224, 0, stream>>>(y1, ga, w2, out);
}

// Round 5
// 76.264 us; speedup vs baseline: 9.7283x; 1.1681x over previous
//
#include <hip/hip_runtime.h>
#include <hip/hip_bf16.h>

#define HH 200
#define WW 176
#define CIN 256
#define CO 28
#define BN_EPS 1e-3f

typedef __attribute__((ext_vector_type(8))) short short8;
typedef __attribute__((ext_vector_type(4))) float f32x4;

static __device__ __forceinline__ ushort f2bf(float f) {
    __hip_bfloat16 h = __float2bfloat16(f);
    return __builtin_bit_cast(ushort, h);
}

// fire-and-forget 16B global->LDS copy (per-lane gsrc, wave-uniform lds base)
#define GLL16(g, l)                                                         \
    __builtin_amdgcn_global_load_lds(                                       \
        (const __attribute__((address_space(1))) void*)(g),                 \
        (__attribute__((address_space(3))) void*)(l), 16, 0, 0)

// ---------------------------------------------------------------------------
// prep: w1b chunk-major [h][t][n][lane][j] (bf16, BN-folded), plus shift[28].
//   co = n*16 + (lane&15), ci = h*32 + (lane>>4)*8 + j
// One chunk h = 9*2*64*8 ushort = 18432 B, contiguous -> global_load_lds-able.
// ---------------------------------------------------------------------------
__global__ void prep_k(const float* __restrict__ w1, const float* __restrict__ gamma,
                       const float* __restrict__ beta, const float* __restrict__ mean,
                       const float* __restrict__ var, ushort* __restrict__ w1b,
                       float* __restrict__ shift)
{
    int idx = blockIdx.x * 256 + threadIdx.x;
    if (idx < CO) {
        float sc = gamma[idx] * rsqrtf(var[idx] + BN_EPS);
        shift[idx] = beta[idx] - mean[idx] * sc;
    }
    if (idx < 8 * 9 * 2 * 64 * 8) {
        int j   = idx & 7;
        int l   = (idx >> 3) & 63;
        int n   = (idx >> 9) & 1;
        int rem = idx >> 10;          // h*9 + t
        int t   = rem % 9;
        int h   = rem / 9;
        int co = n * 16 + (l & 15);
        int ci = h * 32 + (l >> 4) * 8 + j;
        float v = 0.f;
        if (co < CO) {
            float sc = gamma[co] * rsqrtf(var[co] + BN_EPS);
            v = w1[(co * CIN + ci) * 9 + t] * sc;
        }
        w1b[idx] = f2bf(v);
    }
}

// ---------------------------------------------------------------------------
// Implicit-GEMM conv3x3 + BN + ReLU via bf16 MFMA.
// Tile 16x8 px, 4 waves; wave w owns rows {2w,2w+1}, stages ci-octet w.
// x halo 18x10 px x 32ci bf16 in LDS (single buffer, 16B-unit swizzle).
// Weights: per-chunk 18KB block staged via global_load_lds, double-buffered.
// Per chunk: gll W(h+1) + issue x(h+1) -> compute(h) -> bar -> wr x -> bar.
// ---------------------------------------------------------------------------
__global__ __launch_bounds__(256, 3) void conv_mfma_k(
    const float* __restrict__ x, const ushort* __restrict__ w1b,
    const float* __restrict__ shift, float* __restrict__ y1)
{
    __shared__ uint4  sbuf[180 * 4];      // 11520 B  (x halo, bf16 pixel-major)
    __shared__ ushort wls[2][9216];       // 2 x 18432 B (weight chunk dbuf)

    const int tid  = threadIdx.x;
    const int lane = tid & 63;
    const int w    = tid >> 6;            // wave id == ci octet

    // XCD-aware bijective block swizzle (1100 blocks, 8 XCDs)
    const int NB = 11 * 25 * 4;
    const int q = NB / 8, r = NB % 8;     // 137, 4
    const int bid  = blockIdx.x;
    const int xcd  = bid & 7;
    const int rank = bid >> 3;
    const int tile = (xcd < r ? xcd * (q + 1) : r * (q + 1) + (xcd - r) * q) + rank;

    const int tx  = tile % 11;
    const int rem = tile / 11;
    const int ty  = rem % 25;
    const int b   = rem / 25;
    const int x0  = tx * 16, y0 = ty * 8;

    const float* xb = x + (size_t)b * CIN * HH * WW;

    // chunk-invariant per-lane staging geometry (halo 18 wide x 10 tall)
    int  soff[3]; bool sval[3]; bool sp[3];
#pragma unroll
    for (int it = 0; it < 3; ++it) {
        int p = it * 64 + lane;
        sp[it] = p < 180;
        int rr = p / 18, cc = p - rr * 18;
        int gy = y0 + rr - 1, gx = x0 + cc - 1;
        bool v = (gy >= 0) & (gy < HH) & (gx >= 0) & (gx < WW) & sp[it];
        sval[it] = v;
        soff[it] = v ? gy * WW + gx : 0;
    }

    float pre[3][8];

    auto issue_x = [&](int h) {
        const float* pl = xb + (size_t)(h * 32 + w * 8) * (HH * WW);
#pragma unroll
        for (int it = 0; it < 3; ++it) {
            if (sp[it]) {
#pragma unroll
                for (int j = 0; j < 8; ++j)
                    pre[it][j] = pl[(size_t)j * (HH * WW) + soff[it]];
            }
        }
    };

    auto wr_x = [&]() {
#pragma unroll
        for (int it = 0; it < 3; ++it) {
            if (sp[it]) {
                int p = it * 64 + lane;
                ushort u[8];
#pragma unroll
                for (int j = 0; j < 8; ++j)
                    u[j] = sval[it] ? f2bf(pre[it][j]) : (ushort)0;
                uint4 val;
                val.x = (uint)u[0] | ((uint)u[1] << 16);
                val.y = (uint)u[2] | ((uint)u[3] << 16);
                val.z = (uint)u[4] | ((uint)u[5] << 16);
                val.w = (uint)u[6] | ((uint)u[7] << 16);
                sbuf[p * 4 + ((w + p) & 3)] = val;
            }
        }
    };

    // stage weight chunk h into wls[h&1]: 1152 x 16B slots, 18 wave-instrs
    auto gll_w = [&](int h) {
        const ushort* src = w1b + (size_t)h * 9216;
#pragma unroll
        for (int it = 0; it < 5; ++it) {
            int slot = it * 256 + w * 64;        // wave-uniform
            if (slot < 1152)
                GLL16(src + (size_t)(slot + lane) * 8, &wls[h & 1][slot * 8]);
        }
    };

    f32x4 acc[2][2];
#pragma unroll
    for (int m = 0; m < 2; ++m)
#pragma unroll
        for (int n = 0; n < 2; ++n)
            acc[m][n] = (f32x4){0.f, 0.f, 0.f, 0.f};

    auto compute = [&](int h) {
        const ushort* wp = wls[h & 1];
#pragma unroll
        for (int t = 0; t < 9; ++t) {
            const int dy = t / 3 - 1, dx = t % 3 - 1;
            short8 bfr[2];
#pragma unroll
            for (int n = 0; n < 2; ++n)
                bfr[n] = *(const short8*)&wp[(size_t)((t * 2 + n) * 64 + lane) * 8];
#pragma unroll
            for (int m = 0; m < 2; ++m) {
                int p = (2 * w + m + dy + 1) * 18 + (lane & 15) + dx + 1;
                uint4 av = sbuf[p * 4 + (((lane >> 4) + p) & 3)];
                short8 af = __builtin_bit_cast(short8, av);
                acc[m][0] = __builtin_amdgcn_mfma_f32_16x16x32_bf16(af, bfr[0], acc[m][0], 0, 0, 0);
                acc[m][1] = __builtin_amdgcn_mfma_f32_16x16x32_bf16(af, bfr[1], acc[m][1], 0, 0, 0);
            }
        }
    };

    // prologue: weights(0) in flight, x(0) staged
    gll_w(0);
    issue_x(0);
    wr_x();
    __syncthreads();      // drains gll(0) + x stores

    // main loop: 2 barriers per chunk, all global latency hidden under compute
#pragma unroll 1
    for (int h = 0; h < 8; ++h) {
        if (h < 7) {
            gll_w(h + 1);     // fire-and-forget into wls[(h+1)&1]
            issue_x(h + 1);   // x prefetch into registers
        }
        compute(h);
        if (h < 7) {
            __syncthreads();  // all waves done reading sbuf(h)
            wr_x();           // convert + ds_write sbuf(h+1)
            __syncthreads();  // sbuf + wls[(h+1)&1] ready (vmcnt drained)
        }
    }

    // epilogue: + shift, ReLU, store channel-last y1
    const int co0 = lane & 15;
    const int co1 = 16 + co0;
    const float s0 = shift[co0];
    const float s1 = (co1 < CO) ? shift[co1] : 0.f;
#pragma unroll
    for (int m = 0; m < 2; ++m) {
        int gy = y0 + 2 * w + m;
#pragma unroll
        for (int reg = 0; reg < 4; ++reg) {
            int gx = x0 + (lane >> 4) * 4 + reg;
            float* yp = y1 + ((size_t)(b * HH + gy) * WW + gx) * CO;
            float v0 = acc[m][0][reg] + s0;
            yp[co0] = v0 > 0.f ? v0 : 0.f;
            if (co1 < CO) {
                float v1 = acc[m][1][reg] + s1;
                yp[co1] = v1 > 0.f ? v1 : 0.f;
            }
        }
    }
}

// ---------------------------------------------------------------------------
// Sampler: thread = (box, k).  Bilinear sample of conv1x1 output = conv1x1 of
// bilinear samples (linear, bias-free).  Mean over k via LDS reduce.
// ---------------------------------------------------------------------------
__global__ __launch_bounds__(224) void sample_k(
    const float* __restrict__ y1, const float* __restrict__ ga,
    const float* __restrict__ w2, float* __restrict__ out)
{
    __shared__ float red[224];
    const int lb  = threadIdx.x / CO;   // local box 0..7
    const int k   = threadIdx.x % CO;   // window index / channel
    const int box = blockIdx.x * 8 + lb;
    const int b   = box >> 11;          // / 2048

    const float* ap = ga + (size_t)box * 7;
    float xg = ap[0], yg = ap[1], wg = ap[3], lg = ap[4], rg = ap[6];
    float c = cosf(rg), s = sinf(rg);

    const int i = k / 7, j = k % 7;
    float xx = ((float)i * (1.f / 3.f) - 0.5f) * wg;
    float yy = ((float)j * (1.f / 6.f) - 0.5f) * lg;
    float xs = (xx * c + yy * s + xg) * 2.5f;
    float ys = (yy * c - xx * s + yg + 40.f) * 2.5f;

    float x0 = floorf(xs), y0 = floorf(ys);
    float wx = xs - x0,    wy = ys - y0;

    float w2r[CO];
    const float* w2p = w2 + k * CO;
#pragma unroll
    for (int q = 0; q < 7; ++q) {
        float4 t = ((const float4*)w2p)[q];
        w2r[4*q] = t.x; w2r[4*q+1] = t.y; w2r[4*q+2] = t.z; w2r[4*q+3] = t.w;
    }

    float val = 0.f;
    const float* yb = y1 + (size_t)b * HH * WW * CO;
#pragma unroll
    for (int cor = 0; cor < 4; ++cor) {
        float yf = y0 + (float)(cor >> 1);
        float xf = x0 + (float)(cor & 1);
        float cw = ((cor & 1) ? wx : 1.f - wx) * ((cor >> 1) ? wy : 1.f - wy);
        if (yf >= 0.f && yf <= (float)(HH - 1) && xf >= 0.f && xf <= (float)(WW - 1)) {
            int yi = (int)yf, xi = (int)xf;
            const float* p = yb + ((size_t)yi * WW + xi) * CO;
            float d = 0.f;
#pragma unroll
            for (int q = 0; q < 7; ++q) {
                float4 t = ((const float4*)p)[q];
                d = fmaf(w2r[4*q],   t.x, d);
                d = fmaf(w2r[4*q+1], t.y, d);
                d = fmaf(w2r[4*q+2], t.z, d);
                d = fmaf(w2r[4*q+3], t.w, d);
            }
            val = fmaf(cw, d, val);
        }
    }

    red[threadIdx.x] = val;
    __syncthreads();
    if (k == 0) {
        float sum = 0.f;
#pragma unroll
        for (int q = 0; q < CO; ++q) sum += red[lb * CO + q];
        out[box] = sum * (1.f / 28.f);
    }
}

// ---------------------------------------------------------------------------
extern "C" void kernel_launch(void* const* d_in, const int* in_sizes, int n_in,
                              void* d_out, int out_size, void* d_ws, size_t ws_size,
                              hipStream_t stream) {
    const float* x     = (const float*)d_in[0];
    const float* ga    = (const float*)d_in[1];
    const float* w1    = (const float*)d_in[2];
    const float* gamma = (const float*)d_in[3];
    const float* beta  = (const float*)d_in[4];
    const float* mean  = (const float*)d_in[5];
    const float* var   = (const float*)d_in[6];
    const float* w2    = (const float*)d_in[7];
    float* out = (float*)d_out;

    ushort* w1b   = (ushort*)d_ws;                         // 147456 B
    float*  shift = (float*)((char*)d_ws + 147456);        // 112 B
    float*  y1    = (float*)((char*)d_ws + 147968);        // 4*200*176*28 f32

    prep_k<<<(8 * 9 * 2 * 64 * 8 + 255) / 256, 256, 0, stream>>>(
        w1, gamma, beta, mean, var, w1b, shift);

    conv_mfma_k<<<11 * 25 * 4, 256, 0, stream>>>(x, w1b, shift, y1);

    sample_k<<<(4 * 2048) / 8, 224, 0, stream>>>(y1, ga, w2, out);
}